// Round 1
// baseline (298.585 us; speedup 1.0000x reference)
//
#include <hip/hip_runtime.h>

// B=512, P=64, K=8, D=512, T=50000
// out: [B*P, 2*D] fp32
#define BB 512
#define PP 64
#define KK 8
#define DD 512

// One wave (64 lanes) per output row (b,p). Each lane owns 8 d-elements:
// d = lane*4 .. lane*4+3  and  d = 256+lane*4 .. 256+lane*4+3
// so each float4 load instruction is a fully contiguous 1 KB per wave.
__global__ __launch_bounds__(256) void han_meta_kernel(
    const float* __restrict__ inputs,       // [B,P,D]
    const float* __restrict__ title,        // [T,D]
    const int*   __restrict__ nbr_batch,    // [B,P,K]
    const int*   __restrict__ nbr_job,      // [B,P,K]
    const int*   __restrict__ nbr_title,    // [B,P,K]
    const int*   __restrict__ nbr_mask,     // [B,P,K]
    float*       __restrict__ out)          // [B*P, 2*D]
{
    const int lane = threadIdx.x & 63;
    const int wave = threadIdx.x >> 6;
    const int row  = blockIdx.x * 4 + wave;        // in [0, B*P)

    // ---- focal embedding (coalesced) ----
    const float4* inp4 = (const float4*)(inputs + (size_t)row * DD);
    const float4 fa = inp4[lane];        // d = lane*4
    const float4 fb = inp4[lane + 64];   // d = 256 + lane*4

    // ---- neighbor indices: 8 contiguous ints per row, 16B-aligned ----
    const int4* nb4 = (const int4*)(nbr_batch + row * KK);
    const int4* nj4 = (const int4*)(nbr_job   + row * KK);
    const int4* nt4 = (const int4*)(nbr_title + row * KK);
    const int4* nm4 = (const int4*)(nbr_mask  + row * KK);
    int nbk[KK], njk[KK], ntk[KK], nmk[KK];
    *(int4*)&nbk[0] = nb4[0]; *(int4*)&nbk[4] = nb4[1];
    *(int4*)&njk[0] = nj4[0]; *(int4*)&njk[4] = nj4[1];
    *(int4*)&ntk[0] = nt4[0]; *(int4*)&ntk[4] = nt4[1];
    *(int4*)&nmk[0] = nm4[0]; *(int4*)&nmk[4] = nm4[1];

    // ---- attention logits: dot(focal, neighbor) for unmasked k ----
    // mask is wave-uniform (same row for all 64 lanes) -> branch is free.
    float logit[KK];
    #pragma unroll
    for (int k = 0; k < KK; ++k) {
        if (nmk[k]) {
            const float4* g4 = (const float4*)(inputs +
                ((size_t)nbk[k] * PP + (size_t)njk[k]) * DD);
            const float4 ga = g4[lane];
            const float4 gb = g4[lane + 64];
            float d = fa.x*ga.x + fa.y*ga.y + fa.z*ga.z + fa.w*ga.w
                    + fb.x*gb.x + fb.y*gb.y + fb.z*gb.z + fb.w*gb.w;
            // butterfly reduce across the 64-lane wave; result in all lanes
            #pragma unroll
            for (int off = 32; off >= 1; off >>= 1)
                d += __shfl_xor(d, off, 64);
            logit[k] = d;
        } else {
            logit[k] = -1e9f;
        }
    }

    // ---- masked softmax over K=8 (replicated per lane; all scalars) ----
    float m = logit[0];
    #pragma unroll
    for (int k = 1; k < KK; ++k) m = fmaxf(m, logit[k]);
    float e[KK];
    float s = 0.0f;
    #pragma unroll
    for (int k = 0; k < KK; ++k) {
        e[k] = expf(logit[k] - m);
        s += e[k];
    }
    const float inv = 1.0f / s;

    // ---- weighted sum of title embeddings (skip masked: sim==0 exactly) ----
    float4 oa = make_float4(0.f, 0.f, 0.f, 0.f);
    float4 ob = make_float4(0.f, 0.f, 0.f, 0.f);
    #pragma unroll
    for (int k = 0; k < KK; ++k) {
        if (nmk[k]) {
            const float w = e[k] * inv;
            const float4* t4 = (const float4*)(title + (size_t)ntk[k] * DD);
            const float4 ta = t4[lane];
            const float4 tb = t4[lane + 64];
            oa.x += w * ta.x; oa.y += w * ta.y; oa.z += w * ta.z; oa.w += w * ta.w;
            ob.x += w * tb.x; ob.y += w * tb.y; ob.z += w * tb.z; ob.w += w * tb.w;
        }
    }

    // ---- write: [focal(512) | graph(512)] ----
    float4* o4 = (float4*)(out + (size_t)row * (2 * DD));
    o4[lane]       = fa;   // d 0..255
    o4[lane + 64]  = fb;   // d 256..511
    o4[lane + 128] = oa;   // graph 0..255
    o4[lane + 192] = ob;   // graph 256..511
}

extern "C" void kernel_launch(void* const* d_in, const int* in_sizes, int n_in,
                              void* d_out, int out_size, void* d_ws, size_t ws_size,
                              hipStream_t stream) {
    const float* inputs    = (const float*)d_in[0];
    const float* title     = (const float*)d_in[1];
    const int*   nbr_batch = (const int*)d_in[2];
    const int*   nbr_job   = (const int*)d_in[3];
    const int*   nbr_title = (const int*)d_in[4];
    const int*   nbr_mask  = (const int*)d_in[5];
    float*       out       = (float*)d_out;

    // 4 rows (waves) per 256-thread block -> 32768/4 = 8192 blocks
    const int rows = BB * PP;
    dim3 grid(rows / 4);
    dim3 block(256);
    han_meta_kernel<<<grid, block, 0, stream>>>(
        inputs, title, nbr_batch, nbr_job, nbr_title, nbr_mask, out);
}

// Round 2
// 296.451 us; speedup vs baseline: 1.0072x; 1.0072x over previous
//
#include <hip/hip_runtime.h>

// B=512, P=64, K=8, D=512, T=50000
// out: [B*P, 2*D] fp32
#define BB 512
#define PP 64
#define KK 8
#define DD 512

typedef float v4f __attribute__((ext_vector_type(4)));

// One wave (64 lanes) per output row (b,p). Each lane owns 8 d-elements:
// d = lane*4 .. lane*4+3  and  d = 256+lane*4 .. 256+lane*4+3
// so each float4 load instruction is a fully contiguous 1 KB per wave.
//
// Output is write-once / never-re-read: stored with non-temporal stores so
// the 134 MB write stream does not victimize the L3-resident gather tables
// (inputs 64 MB + title 102 MB fit in the 256 MB Infinity Cache only if the
// write stream bypasses it).
__global__ __launch_bounds__(256) void han_meta_kernel(
    const float* __restrict__ inputs,       // [B,P,D]
    const float* __restrict__ title,        // [T,D]
    const int*   __restrict__ nbr_batch,    // [B,P,K]
    const int*   __restrict__ nbr_job,      // [B,P,K]
    const int*   __restrict__ nbr_title,    // [B,P,K]
    const int*   __restrict__ nbr_mask,     // [B,P,K]
    float*       __restrict__ out)          // [B*P, 2*D]
{
    const int lane = threadIdx.x & 63;
    const int wave = threadIdx.x >> 6;
    const int row  = blockIdx.x * 4 + wave;        // in [0, B*P)

    // ---- focal embedding (coalesced) ----
    const float4* inp4 = (const float4*)(inputs + (size_t)row * DD);
    const float4 fa = inp4[lane];        // d = lane*4
    const float4 fb = inp4[lane + 64];   // d = 256 + lane*4

    // ---- neighbor indices: 8 contiguous ints per row, 16B-aligned ----
    const int4* nb4 = (const int4*)(nbr_batch + row * KK);
    const int4* nj4 = (const int4*)(nbr_job   + row * KK);
    const int4* nt4 = (const int4*)(nbr_title + row * KK);
    const int4* nm4 = (const int4*)(nbr_mask  + row * KK);
    int nbk[KK], njk[KK], ntk[KK], nmk[KK];
    *(int4*)&nbk[0] = nb4[0]; *(int4*)&nbk[4] = nb4[1];
    *(int4*)&njk[0] = nj4[0]; *(int4*)&njk[4] = nj4[1];
    *(int4*)&ntk[0] = nt4[0]; *(int4*)&ntk[4] = nt4[1];
    *(int4*)&nmk[0] = nm4[0]; *(int4*)&nmk[4] = nm4[1];

    // ---- attention logits: dot(focal, neighbor) for unmasked k ----
    // mask is wave-uniform (same row for all 64 lanes) -> branch is free.
    float logit[KK];
    #pragma unroll
    for (int k = 0; k < KK; ++k) {
        if (nmk[k]) {
            const float4* g4 = (const float4*)(inputs +
                ((size_t)nbk[k] * PP + (size_t)njk[k]) * DD);
            const float4 ga = g4[lane];
            const float4 gb = g4[lane + 64];
            float d = fa.x*ga.x + fa.y*ga.y + fa.z*ga.z + fa.w*ga.w
                    + fb.x*gb.x + fb.y*gb.y + fb.z*gb.z + fb.w*gb.w;
            // butterfly reduce across the 64-lane wave; result in all lanes
            #pragma unroll
            for (int off = 32; off >= 1; off >>= 1)
                d += __shfl_xor(d, off, 64);
            logit[k] = d;
        } else {
            logit[k] = -1e9f;
        }
    }

    // ---- masked softmax over K=8 (replicated per lane; all scalars) ----
    float m = logit[0];
    #pragma unroll
    for (int k = 1; k < KK; ++k) m = fmaxf(m, logit[k]);
    float e[KK];
    float s = 0.0f;
    #pragma unroll
    for (int k = 0; k < KK; ++k) {
        e[k] = expf(logit[k] - m);
        s += e[k];
    }
    const float inv = 1.0f / s;

    // ---- weighted sum of title embeddings (skip masked: sim==0 exactly) ----
    float4 oa = make_float4(0.f, 0.f, 0.f, 0.f);
    float4 ob = make_float4(0.f, 0.f, 0.f, 0.f);
    #pragma unroll
    for (int k = 0; k < KK; ++k) {
        if (nmk[k]) {
            const float w = e[k] * inv;
            const float4* t4 = (const float4*)(title + (size_t)ntk[k] * DD);
            const float4 ta = t4[lane];
            const float4 tb = t4[lane + 64];
            oa.x += w * ta.x; oa.y += w * ta.y; oa.z += w * ta.z; oa.w += w * ta.w;
            ob.x += w * tb.x; ob.y += w * tb.y; ob.z += w * tb.z; ob.w += w * tb.w;
        }
    }

    // ---- write: [focal(512) | graph(512)] -- non-temporal (write-once) ----
    v4f* o4 = (v4f*)(out + (size_t)row * (2 * DD));
    v4f va = {fa.x, fa.y, fa.z, fa.w};
    v4f vb = {fb.x, fb.y, fb.z, fb.w};
    v4f vc = {oa.x, oa.y, oa.z, oa.w};
    v4f vd = {ob.x, ob.y, ob.z, ob.w};
    __builtin_nontemporal_store(va, o4 + lane);        // d 0..255
    __builtin_nontemporal_store(vb, o4 + lane + 64);   // d 256..511
    __builtin_nontemporal_store(vc, o4 + lane + 128);  // graph 0..255
    __builtin_nontemporal_store(vd, o4 + lane + 192);  // graph 256..511
}

extern "C" void kernel_launch(void* const* d_in, const int* in_sizes, int n_in,
                              void* d_out, int out_size, void* d_ws, size_t ws_size,
                              hipStream_t stream) {
    const float* inputs    = (const float*)d_in[0];
    const float* title     = (const float*)d_in[1];
    const int*   nbr_batch = (const int*)d_in[2];
    const int*   nbr_job   = (const int*)d_in[3];
    const int*   nbr_title = (const int*)d_in[4];
    const int*   nbr_mask  = (const int*)d_in[5];
    float*       out       = (float*)d_out;

    // 4 rows (waves) per 256-thread block -> 32768/4 = 8192 blocks
    const int rows = BB * PP;
    dim3 grid(rows / 4);
    dim3 block(256);
    han_meta_kernel<<<grid, block, 0, stream>>>(
        inputs, title, nbr_batch, nbr_job, nbr_title, nbr_mask, out);
}